// Round 1
// baseline (111.991 us; speedup 1.0000x reference)
//
#include <hip/hip_runtime.h>

// Problem constants (from reference setup_inputs)
constexpr int Bn = 16, Cn = 4, Hn = 512, Wn = 512, Nn = 8192;
constexpr int BLOCK = 256;
constexpr int GRID  = 1024;            // 128 blocks per XCD -> 4 blocks/CU, 16 waves/CU
constexpr int PHASES = 4;              // plane-pair sweep order retained for L2 affinity

typedef int iv4 __attribute__((ext_vector_type(4)));

// good-interval counts per class c: set0 [1,1,2,1], set1 [0,1,0,2]
__device__ __forceinline__ int good_of(int s, int c) {
    return (s == 0) ? ((c == 2) ? 2 : 1)
                    : ((c == 1) ? 1 : ((c == 3) ? 2 : 0));
}

__global__ __launch_bounds__(BLOCK) void bd_gather(
        const float* __restrict__ pred,
        const iv4* __restrict__ iv0,
        const iv4* __restrict__ iv1,
        float* __restrict__ partials) {
    // XCD-affinity: blocks with blockIdx%8==x land on XCD x (round-robin dispatch).
    // Each XCD owns the 8 planes p ≡ x (mod 8). Phase ORDER is kept for temporal
    // locality, but there are NO barriers: __syncthreads forces a vmcnt(0) drain
    // (compiler-inserted before s_barrier), which serialized all 4 phases'
    // memory latency. Instead: preload all 4 interval quads (independent,
    // non-temporal so the 16 MiB stream doesn't evict pred lines from L2),
    // then issue all 8 gathers; pred is L3-resident so extra L2 misses are cheap.
    const int m   = blockIdx.x;
    const int xcd = m & 7;
    const int r   = m >> 3;                      // [0,128)
    const int idx = r * BLOCK + threadIdx.x;     // [0,32768)
    const int u   = idx >> 14;                   // plane of the phase pair (block-uniform)
    const int s   = (idx >> 13) & 1;             // interval set (block-uniform)
    const int e   = idx & (Nn - 1);              // entry within plane

    const iv4* __restrict__ iv = s ? iv1 : iv0;

    // 1) All interval quads in flight at once (4 independent 16B coalesced loads).
    iv4 A[PHASES];
    #pragma unroll
    for (int j = 0; j < PHASES; ++j) {
        const int p = (2 * j + u) * 8 + xcd;     // plane = b*C + c
        A[j] = __builtin_nontemporal_load(&iv[p * Nn + e]);
    }

    // 2) All 8 gathers issue as soon as their quad lands (max MLP).
    float bs[PHASES], ds[PHASES];
    #pragma unroll
    for (int j = 0; j < PHASES; ++j) {
        const int p = (2 * j + u) * 8 + xcd;
        const float* __restrict__ plane = pred + (size_t)p * (Hn * Wn);
        bs[j] = plane[(A[j].x << 9) + A[j].y];   // W=512 -> <<9
        ds[j] = plane[(A[j].z << 9) + A[j].w];
    }

    // 3) Accumulate in the same order as before (bit-identical result).
    float acc = 0.0f;
    #pragma unroll
    for (int j = 0; j < PHASES; ++j) {
        const int p = (2 * j + u) * 8 + xcd;
        const int c = p & (Cn - 1);
        float d = bs[j] - ds[j]; d *= d;
        acc += (e < good_of(s, c)) ? (1.0f - d) : d;
    }

    // wave-64 butterfly reduce
    #pragma unroll
    for (int off = 32; off > 0; off >>= 1)
        acc += __shfl_down(acc, off, 64);

    __shared__ float wsum[BLOCK / 64];
    const int lane = threadIdx.x & 63;
    const int wave = threadIdx.x >> 6;
    if (lane == 0) wsum[wave] = acc;
    __syncthreads();
    if (threadIdx.x == 0)
        partials[blockIdx.x] = wsum[0] + wsum[1] + wsum[2] + wsum[3];
}

__global__ __launch_bounds__(BLOCK) void bd_final(
        const float* __restrict__ partials,
        float* __restrict__ out) {
    float acc = 0.0f;
    #pragma unroll
    for (int i = 0; i < GRID / BLOCK; ++i)
        acc += partials[threadIdx.x + i * BLOCK];

    #pragma unroll
    for (int off = 32; off > 0; off >>= 1)
        acc += __shfl_down(acc, off, 64);

    __shared__ float wsum[BLOCK / 64];
    const int lane = threadIdx.x & 63;
    const int wave = threadIdx.x >> 6;
    if (lane == 0) wsum[wave] = acc;
    __syncthreads();
    if (threadIdx.x == 0)
        out[0] = wsum[0] + wsum[1] + wsum[2] + wsum[3];
}

extern "C" void kernel_launch(void* const* d_in, const int* in_sizes, int n_in,
                              void* d_out, int out_size, void* d_ws, size_t ws_size,
                              hipStream_t stream) {
    const float* pred = (const float*)d_in[0];
    const iv4*   iv0  = (const iv4*)d_in[1];
    const iv4*   iv1  = (const iv4*)d_in[2];
    float* out      = (float*)d_out;
    float* partials = (float*)d_ws;              // GRID floats = 4 KiB scratch

    bd_gather<<<GRID, BLOCK, 0, stream>>>(pred, iv0, iv1, partials);
    bd_final<<<1, BLOCK, 0, stream>>>(partials, out);
}

// Round 2
// 108.542 us; speedup vs baseline: 1.0318x; 1.0318x over previous
//
#include <hip/hip_runtime.h>

// Problem constants (from reference setup_inputs)
constexpr int Bn = 16, Cn = 4, Hn = 512, Wn = 512, Nn = 8192;
constexpr int BLOCK = 256;
constexpr int GRID  = 1024;            // 128 blocks per XCD -> 4 blocks/CU, 16 waves/CU
constexpr int PHASES = 4;              // 2 planes per XCD per phase -> 2 MiB hot << 4 MiB L2

typedef int iv4 __attribute__((ext_vector_type(4)));

// good-interval counts per class c: set0 [1,1,2,1], set1 [0,1,0,2]
__device__ __forceinline__ int good_of(int s, int c) {
    return (s == 0) ? ((c == 2) ? 2 : 1)
                    : ((c == 1) ? 1 : ((c == 3) ? 2 : 0));
}

__global__ __launch_bounds__(BLOCK) void bd_gather(
        const float* __restrict__ pred,
        const iv4* __restrict__ iv0,
        const iv4* __restrict__ iv1,
        float* __restrict__ partials) {
    // XCD-affinity: blocks with blockIdx%8==x land on XCD x (round-robin dispatch).
    // Each XCD owns the 8 planes p ≡ x (mod 8), swept in 4 phases of 2 planes so
    // only ~2 MiB of pred is hot per XCD L2 (round-1 showed 8 MiB-at-once thrashes).
    // Phases are separated by RAW s_barrier (no compiler vmcnt(0) drain, unlike
    // __syncthreads) and software-pipelined depth-1: phase j+1's gathers are in
    // flight while phase j is consumed, so latency never serializes the phases.
    const int m   = blockIdx.x;
    const int xcd = m & 7;
    const int r   = m >> 3;                      // [0,128)
    const int idx = r * BLOCK + threadIdx.x;     // [0,32768)
    const int u   = idx >> 14;                   // plane of the phase pair (block-uniform)
    const int s   = (idx >> 13) & 1;             // interval set (block-uniform)
    const int e   = idx & (Nn - 1);              // entry within plane

    const iv4* __restrict__ iv = s ? iv1 : iv0;

    // All interval quads in flight up-front (independent 16B coalesced loads,
    // non-temporal so the 16 MiB stream doesn't evict pred lines from L2).
    iv4 A[PHASES];
    #pragma unroll
    for (int j = 0; j < PHASES; ++j) {
        const int p = (2 * j + u) * 8 + xcd;     // plane = b*C + c
        A[j] = __builtin_nontemporal_load(&iv[p * Nn + e]);
    }

    float bs[PHASES], ds[PHASES];

    // Prologue: phase 0 gathers.
    {
        const float* __restrict__ plane = pred + (size_t)(u * 8 + xcd) * (Hn * Wn);
        bs[0] = plane[(A[0].x << 9) + A[0].y];   // W=512 -> <<9
        ds[0] = plane[(A[0].z << 9) + A[0].w];
    }

    float acc = 0.0f;
    #pragma unroll
    for (int j = 0; j < PHASES; ++j) {
        // Issue next phase's gathers before consuming this phase (stay in flight
        // across the raw barrier; compiler emits partial vmcnt for the consume).
        if (j + 1 < PHASES) {
            const int pn = (2 * (j + 1) + u) * 8 + xcd;
            const float* __restrict__ plane = pred + (size_t)pn * (Hn * Wn);
            bs[j + 1] = plane[(A[j + 1].x << 9) + A[j + 1].y];
            ds[j + 1] = plane[(A[j + 1].z << 9) + A[j + 1].w];
        }
        const int p = (2 * j + u) * 8 + xcd;
        const int c = p & (Cn - 1);
        float d = bs[j] - ds[j]; d *= d;
        acc += (e < good_of(s, c)) ? (1.0f - d) : d;   // same order as before: bit-identical
        if (j + 1 < PHASES)
            __builtin_amdgcn_s_barrier();        // align phases, NO vmcnt(0) drain
    }

    // wave-64 butterfly reduce (unchanged)
    #pragma unroll
    for (int off = 32; off > 0; off >>= 1)
        acc += __shfl_down(acc, off, 64);

    __shared__ float wsum[BLOCK / 64];
    const int lane = threadIdx.x & 63;
    const int wave = threadIdx.x >> 6;
    if (lane == 0) wsum[wave] = acc;
    __syncthreads();
    if (threadIdx.x == 0)
        partials[blockIdx.x] = wsum[0] + wsum[1] + wsum[2] + wsum[3];
}

__global__ __launch_bounds__(BLOCK) void bd_final(
        const float* __restrict__ partials,
        float* __restrict__ out) {
    float acc = 0.0f;
    #pragma unroll
    for (int i = 0; i < GRID / BLOCK; ++i)
        acc += partials[threadIdx.x + i * BLOCK];

    #pragma unroll
    for (int off = 32; off > 0; off >>= 1)
        acc += __shfl_down(acc, off, 64);

    __shared__ float wsum[BLOCK / 64];
    const int lane = threadIdx.x & 63;
    const int wave = threadIdx.x >> 6;
    if (lane == 0) wsum[wave] = acc;
    __syncthreads();
    if (threadIdx.x == 0)
        out[0] = wsum[0] + wsum[1] + wsum[2] + wsum[3];
}

extern "C" void kernel_launch(void* const* d_in, const int* in_sizes, int n_in,
                              void* d_out, int out_size, void* d_ws, size_t ws_size,
                              hipStream_t stream) {
    const float* pred = (const float*)d_in[0];
    const iv4*   iv0  = (const iv4*)d_in[1];
    const iv4*   iv1  = (const iv4*)d_in[2];
    float* out      = (float*)d_out;
    float* partials = (float*)d_ws;              // GRID floats = 4 KiB scratch

    bd_gather<<<GRID, BLOCK, 0, stream>>>(pred, iv0, iv1, partials);
    bd_final<<<1, BLOCK, 0, stream>>>(partials, out);
}